// Round 3
// baseline (159.822 us; speedup 1.0000x reference)
//
#include <hip/hip_runtime.h>
#include <stdint.h>

#define SEQ 64
#define D 28
#define EMB 784   // 28*28
#define NW 4      // waves per block (one block = one sentence)
#define CH 16     // per-wave chain length: 4 waves x 16 words = 64
#define BUFF 832  // B-buffer floats: 3328 B = exact DMA coverage (3*1024+256)
#define SCRW 36   // combine-scratch row stride (floats); 2-way-free banks

typedef float float4v __attribute__((ext_vector_type(4)));
typedef __bf16 bf16x8 __attribute__((ext_vector_type(8)));

union FragU { unsigned u[4]; bf16x8 v; };

__device__ __forceinline__ unsigned fbits(float x) { union { float f; unsigned u; } t; t.f = x; return t.u; }
__device__ __forceinline__ float fof(unsigned u) { union { unsigned u; float f; } t; t.u = u; return t.f; }

// Split 8 fp32 (k-order) into hi/lo bf16 fragments (truncation split:
// x = hi + lo + O(2^-16 |x|); MFMA computes hi*hi + hi*lo + lo*hi).
// Verbatim from the passing kernel.
__device__ __forceinline__ void split_frags(const float x[8], bf16x8& hi, bf16x8& lo)
{
    FragU H, L;
#pragma unroll
    for (int p = 0; p < 4; ++p) {
        unsigned ua = fbits(x[2 * p]), ub = fbits(x[2 * p + 1]);
        H.u[p] = (ua >> 16) | (ub & 0xFFFF0000u);
        unsigned la = fbits(x[2 * p]     - fof(ua & 0xFFFF0000u));
        unsigned lb = fbits(x[2 * p + 1] - fof(ub & 0xFFFF0000u));
        L.u[p] = (la >> 16) | (lb & 0xFFFF0000u);
    }
    hi = H.v; lo = L.v;
}

struct AB { bf16x8 h, l; };

// Frag from 4 fp32 in k-slots t=0..3; slots t=4..7 zero (constant-folds).
__device__ __forceinline__ AB make_frag4(const float y[4])
{
    float x[8] = { y[0], y[1], y[2], y[3], 0.f, 0.f, 0.f, 0.f };
    AB r; split_frags(x, r.h, r.l); return r;
}

// ---- async global->LDS DMA of one 3136 B row (+192 B tail overread, stays
// within allocation slack; lands in LDS bytes [3136,3328), never read).
// Verbatim from the passing kernel.
__device__ __forceinline__ void dma_row(const float* grow, float* lbuf, int lane)
{
    const char* g16 = (const char*)grow + lane * 16;
    const char* g4  = (const char*)grow + 3072 + lane * 4;
    char* l = (char*)lbuf;
    __builtin_amdgcn_global_load_lds((const __attribute__((address_space(1))) void*)(g16),
                                     (__attribute__((address_space(3))) void*)(l), 16, 0, 0);
    __builtin_amdgcn_global_load_lds((const __attribute__((address_space(1))) void*)(g16 + 1024),
                                     (__attribute__((address_space(3))) void*)(l + 1024), 16, 0, 0);
    __builtin_amdgcn_global_load_lds((const __attribute__((address_space(1))) void*)(g16 + 2048),
                                     (__attribute__((address_space(3))) void*)(l + 2048), 16, 0, 0);
    __builtin_amdgcn_global_load_lds((const __attribute__((address_space(1))) void*)(g4),
                                     (__attribute__((address_space(3))) void*)(l + 3072), 4, 0, 0);
}

// ================= transpose-space step =================
// acc holds T = C^T as 2x2 16x16 D-frags (verified layout: col=lane&15,
// row=(lane>>4)*4+reg). Step computes T_new = mat^T * T  (== C_new = C*mat).
// k-slot bijection for the verified 16x16x32 MFMA: slot (quad, t<=3) -> real
// row k = 16*KB + 4*quad + t; slots t>=4 are zero on BOTH operands; rows
// k>=28 zeroed via A (quad==3, KB==1). B operand comes from acc IN-LANE:
// B[k][n=16Co+c] = T[16KB+4q+t][16Co+c] = acc[KB][Co][t]  — the D-frag row
// mapping (4q+i) coincides with the B-frag k mapping (4q+t). No LDS round
// trip, no cross-lane exchange.
__device__ __forceinline__ void stepT(const float* mat, int stride,
                                      float4v acc[2][2], int lane)
{
    const int c = lane & 15;
    const int quad = lane >> 4;
    const bool q3 = (quad == 3);

    // A-frags: A[m=16Ro+c][k] = mat[k*stride + m]  (strided b32, 2-way banks)
    float av[2][2][4];
#pragma unroll
    for (int KB = 0; KB < 2; ++KB)
#pragma unroll
        for (int t = 0; t < 4; ++t) {
            int k = 16 * KB + 4 * quad + t;
            if (k > 27) k = 27;            // clamp (value zeroed below)
#pragma unroll
            for (int Ro = 0; Ro < 2; ++Ro)
                av[Ro][KB][t] = mat[k * stride + 16 * Ro + c];
        }

    // B-frags from acc, fully in-lane (reads acc before any acc write)
    AB Bf[2][2];
#pragma unroll
    for (int KB = 0; KB < 2; ++KB)
#pragma unroll
        for (int Co = 0; Co < 2; ++Co) {
            float y[4] = { acc[KB][Co][0], acc[KB][Co][1], acc[KB][Co][2], acc[KB][Co][3] };
            Bf[KB][Co] = make_frag4(y);
        }

    AB Af[2][2];
#pragma unroll
    for (int Ro = 0; Ro < 2; ++Ro)
#pragma unroll
        for (int KB = 0; KB < 2; ++KB) {
            float y[4] = { av[Ro][KB][0], av[Ro][KB][1], av[Ro][KB][2], av[Ro][KB][3] };
            if (q3 && KB == 1) { y[0] = y[1] = y[2] = y[3] = 0.f; }  // k=28..31
            Af[Ro][KB] = make_frag4(y);
        }

#pragma unroll
    for (int Ro = 0; Ro < 2; ++Ro)
#pragma unroll
        for (int Co = 0; Co < 2; ++Co) {
            float4v d = {0.f, 0.f, 0.f, 0.f};
#pragma unroll
            for (int KB = 0; KB < 2; ++KB) {
                d = __builtin_amdgcn_mfma_f32_16x16x32_bf16(Af[Ro][KB].h, Bf[KB][Co].h, d, 0, 0, 0);
                d = __builtin_amdgcn_mfma_f32_16x16x32_bf16(Af[Ro][KB].h, Bf[KB][Co].l, d, 0, 0, 0);
                d = __builtin_amdgcn_mfma_f32_16x16x32_bf16(Af[Ro][KB].l, Bf[KB][Co].h, d, 0, 0, 0);
            }
            acc[Ro][Co] = d;
        }
}

// ================= chain engine (transpose space) =================
// acc = M0^T; then acc <- Mj^T * acc for j=1..CNT-1. Double-buffered DMA.
template <int CNT, typename F>
__device__ __forceinline__ void chainT(F rowptr, float* B0, float* B1,
                                       float4v acc[2][2], int lane)
{
    const int c = lane & 15;
    const int quad = lane >> 4;

    dma_row(rowptr(0), B0, lane);
    dma_row(rowptr(1), B1, lane);
    __builtin_amdgcn_s_waitcnt(0x0074);  // vmcnt(4): row0 landed, row1 in flight

    // init: acc = M0^T: acc[R][Cc][i] = M0[16Cc+c][16R+4q+i] (b128 reads,
    // row clamped to 27 -> junk only in T pad cols, masked at store; pad
    // rows of T get A-side zeros every step).
#pragma unroll
    for (int R = 0; R < 2; ++R)
#pragma unroll
        for (int Cc = 0; Cc < 2; ++Cc) {
            int rcl = 16 * Cc + c; if (rcl > 27) rcl = 27;
            acc[R][Cc] = *(const float4v*)&B0[rcl * D + 16 * R + 4 * quad];
        }
    __builtin_amdgcn_s_waitcnt(0xC07F);  // drain init reads before B0 re-DMA

#pragma unroll 1
    for (int j = 1; j < CNT; ++j) {
        const int jn = (j + 1 < CNT) ? (j + 1) : j;  // last step re-issues row j
        float* nB = (j & 1) ? B0 : B1;   // buffer for row j+1
        float* cB = (j & 1) ? B1 : B0;   // buffer holding row j
        dma_row(rowptr(jn), nB, lane);

        __builtin_amdgcn_sched_barrier(0);
        __builtin_amdgcn_s_waitcnt(0x0074);  // vmcnt(4) lgkmcnt(0)
        __builtin_amdgcn_sched_barrier(0);

        stepT(cB, D, acc, lane);
    }
}

// ================= fused kernel: one block per sentence =================
// 4 waves; wave w computes T_w = (prod of words 16w..16w+15)^T in registers,
// publishes T_w row-major to its LDS region, then all waves redundantly
// combine X = P0*P1*P2*P3 via stepT(mat = T_j) (mat^T = P_j -> left-multiply)
// and wave 0 stores. No CT tiles: LDS = 4*2*3328 = 26.6 KB.
__global__ __launch_bounds__(NW * 64, 1) void w2m_fusedT(
    const int* __restrict__ sent,
    const float* __restrict__ table,
    float* __restrict__ out)
{
    __shared__ float SH[NW * 2 * BUFF] __attribute__((aligned(16)));
    const int lane = threadIdx.x & 63;
    const int wid  = threadIdx.x >> 6;   // 0..3
    const int b = blockIdx.x;

    float* B0 = &SH[wid * 2 * BUFF];
    float* B1 = B0 + BUFF;

    const int myidx = sent[b * SEQ + CH * wid + (lane & (CH - 1))];
    int jl[CH];
#pragma unroll
    for (int j = 0; j < CH; ++j) jl[j] = __builtin_amdgcn_readlane(myidx, j);

    float4v acc[2][2];
    chainT<CH>([&](int j) { return table + (size_t)jl[j] * EMB; },
               B0, B1, acc, lane);

    const int c = lane & 15;
    const int quad = lane >> 4;

    // publish T_w row-major (stride 36) into own region (overwrites B-bufs;
    // region 1664 floats >= 32*36 = 1152). Drain DMA first: last step
    // re-issued a row into B0 which this overwrites.
    __builtin_amdgcn_s_waitcnt(0x0070);  // vmcnt(0) lgkmcnt(0)
    __builtin_amdgcn_sched_barrier(0);
    float* SCR = &SH[wid * 2 * BUFF];
#pragma unroll
    for (int R = 0; R < 2; ++R)
#pragma unroll
        for (int Cc = 0; Cc < 2; ++Cc)
#pragma unroll
            for (int i = 0; i < 4; ++i)
                SCR[(16 * R + 4 * quad + i) * SCRW + 16 * Cc + c] = acc[R][Cc][i];
    __syncthreads();

    // combine (redundant on all waves): X = P3, then X = Pj*X for j=2,1,0.
    // X init: acc[R][Cc][i] = P3[16R+4q+i][16Cc+c] = T3[16Cc+c][16R+4q+i].
    const float* S3 = &SH[3 * 2 * BUFF];
#pragma unroll
    for (int R = 0; R < 2; ++R)
#pragma unroll
        for (int Cc = 0; Cc < 2; ++Cc)
            acc[R][Cc] = *(const float4v*)&S3[(16 * Cc + c) * SCRW + 16 * R + 4 * quad];

#pragma unroll 1
    for (int j = 2; j >= 0; --j)
        stepT(&SH[j * 2 * BUFF], SCRW, acc, lane);

    // store S = X: acc[R][Cc][i] = S[16R+4q+i][16Cc+c]; mask pads.
    if (wid == 0) {
        float* orow = out + (size_t)b * EMB;
#pragma unroll
        for (int R = 0; R < 2; ++R)
#pragma unroll
            for (int Cc = 0; Cc < 2; ++Cc)
#pragma unroll
                for (int i = 0; i < 4; ++i) {
                    const int row = 16 * R + 4 * quad + i;
                    const int col = 16 * Cc + c;
                    if (row < D && col < D) orow[row * D + col] = acc[R][Cc][i];
                }
    }
}

extern "C" void kernel_launch(void* const* d_in, const int* in_sizes, int n_in,
                              void* d_out, int out_size, void* d_ws, size_t ws_size,
                              hipStream_t stream) {
    const int* sent = (const int*)d_in[0];
    const float* table = (const float*)d_in[1];
    float* out = (float*)d_out;
    const int batch = in_sizes[0] / SEQ;                  // 1024
    (void)d_ws; (void)ws_size;                            // workspace unused

    hipLaunchKernelGGL(w2m_fusedT, dim3(batch), dim3(NW * 64), 0, stream,
                       sent, table, out);
}

// Round 5
// 153.266 us; speedup vs baseline: 1.0428x; 1.0428x over previous
//
#include <hip/hip_runtime.h>
#include <stdint.h>

#define SEQ 64
#define D 28
#define EMB 784   // 28*28
#define NW 4      // waves per block (one block = one sentence)
#define CH 16     // per-wave chain length: 4 waves x 16 words = 64
#define BUFF 832  // B-buffer floats: 3328 B = exact DMA coverage (3*1024+256)
#define SCRW 36   // combine-scratch row stride (floats); 2-way-free banks

typedef float float4v __attribute__((ext_vector_type(4)));
typedef __bf16 bf16x8 __attribute__((ext_vector_type(8)));

union FragU { unsigned u[4]; bf16x8 v; };

__device__ __forceinline__ unsigned fbits(float x) { union { float f; unsigned u; } t; t.f = x; return t.u; }
__device__ __forceinline__ float fof(unsigned u) { union { unsigned u; float f; } t; t.u = u; return t.f; }

// Truncation hi/lo split of 4 fp32 into packed bf16 pairs (x0 in low half).
// EXACTLY the arithmetic of the R2/R3 harness-verified split_frags
// (hi = truncate(x), lo = bf16_trunc(x - hi)); only regrouped 8->4 lanes.
// NO v_cvt_pk (R4 post-mortem: its operand/rounding semantics on gfx950 are
// unverified and the failure signature matched garbage lo terms).
struct HL4 { unsigned h01, h23, l01, l23; };
__device__ __forceinline__ HL4 hilo4(float x0, float x1, float x2, float x3) {
    unsigned u0 = fbits(x0), u1 = fbits(x1), u2 = fbits(x2), u3 = fbits(x3);
    HL4 r;
    r.h01 = (u0 >> 16) | (u1 & 0xFFFF0000u);
    r.h23 = (u2 >> 16) | (u3 & 0xFFFF0000u);
    unsigned l0 = fbits(x0 - fof(u0 & 0xFFFF0000u));
    unsigned l1 = fbits(x1 - fof(u1 & 0xFFFF0000u));
    unsigned l2 = fbits(x2 - fof(u2 & 0xFFFF0000u));
    unsigned l3 = fbits(x3 - fof(u3 & 0xFFFF0000u));
    r.l01 = (l0 >> 16) | (l1 & 0xFFFF0000u);
    r.l23 = (l2 >> 16) | (l3 & 0xFFFF0000u);
    return r;
}

// ---- async global->LDS DMA of one 3136 B row (+192 B tail overread, stays
// within allocation slack; lands in LDS bytes [3136,3328), never read).
__device__ __forceinline__ void dma_row(const float* grow, float* lbuf, int lane)
{
    const char* g16 = (const char*)grow + lane * 16;
    const char* g4  = (const char*)grow + 3072 + lane * 4;
    char* l = (char*)lbuf;
    __builtin_amdgcn_global_load_lds((const __attribute__((address_space(1))) void*)(g16),
                                     (__attribute__((address_space(3))) void*)(l), 16, 0, 0);
    __builtin_amdgcn_global_load_lds((const __attribute__((address_space(1))) void*)(g16 + 1024),
                                     (__attribute__((address_space(3))) void*)(l + 1024), 16, 0, 0);
    __builtin_amdgcn_global_load_lds((const __attribute__((address_space(1))) void*)(g16 + 2048),
                                     (__attribute__((address_space(3))) void*)(l + 2048), 16, 0, 0);
    __builtin_amdgcn_global_load_lds((const __attribute__((address_space(1))) void*)(g4),
                                     (__attribute__((address_space(3))) void*)(l + 3072), 4, 0, 0);
}

// ================= transpose-space step (two-term MFMA packing) ===========
// acc <- mat^T * acc, acc in the R3-verified D-frag orientation.
// k-slot map (identical on A and B, per lane with quad q):
//   physical slot t=0..3  <-> logical k = 16KB+4q+t  (HI parts)
//   physical slot t=4..7  <-> SAME logical k         (A=lo, B=hi / B2=0)
//   MFMA1: A={Ah|Al}, B={Bh|Bh}  -> Ah*Bh + Al*Bh
//   MFMA2: A={Ah|Al}, B={Bl|0}   -> Ah*Bl
// = same 3 product terms as R3's verified 3-MFMA form, 16 MFMAs/step.
// B operand comes from acc fully IN-LANE (D-frag row map == B-frag k map,
// established by R3 passing). Logical k=28..31 zeroed on the A side (q3,KB=1);
// chain callers pass a1 pre-clamped in-bounds.
template<int STRIDE>
__device__ __forceinline__ void stepT(const float* a0, const float* a1,
                                      float4v acc[2][2], bool q3)
{
    float av[2][2][4];
#pragma unroll
    for (int t = 0; t < 4; ++t)
#pragma unroll
        for (int Ro = 0; Ro < 2; ++Ro) {
            av[Ro][0][t] = a0[t * STRIDE + 16 * Ro];
            av[Ro][1][t] = a1[t * STRIDE + 16 * Ro];
        }
#pragma unroll
    for (int Ro = 0; Ro < 2; ++Ro)
#pragma unroll
        for (int t = 0; t < 4; ++t)
            av[Ro][1][t] = q3 ? 0.f : av[Ro][1][t];   // logical k=28..31 -> 0

    FragU Af[2][2];
#pragma unroll
    for (int Ro = 0; Ro < 2; ++Ro)
#pragma unroll
        for (int KB = 0; KB < 2; ++KB) {
            HL4 h = hilo4(av[Ro][KB][0], av[Ro][KB][1], av[Ro][KB][2], av[Ro][KB][3]);
            Af[Ro][KB].u[0] = h.h01; Af[Ro][KB].u[1] = h.h23;
            Af[Ro][KB].u[2] = h.l01; Af[Ro][KB].u[3] = h.l23;
        }

    FragU Bd[2][2], B2[2][2];
#pragma unroll
    for (int KB = 0; KB < 2; ++KB)
#pragma unroll
        for (int Co = 0; Co < 2; ++Co) {
            HL4 h = hilo4(acc[KB][Co][0], acc[KB][Co][1], acc[KB][Co][2], acc[KB][Co][3]);
            Bd[KB][Co].u[0] = h.h01; Bd[KB][Co].u[1] = h.h23;
            Bd[KB][Co].u[2] = h.h01; Bd[KB][Co].u[3] = h.h23;
            B2[KB][Co].u[0] = h.l01; B2[KB][Co].u[1] = h.l23;
            B2[KB][Co].u[2] = 0u;    B2[KB][Co].u[3] = 0u;
        }

#pragma unroll
    for (int Ro = 0; Ro < 2; ++Ro)
#pragma unroll
        for (int Co = 0; Co < 2; ++Co) {
            float4v d = {0.f, 0.f, 0.f, 0.f};
#pragma unroll
            for (int KB = 0; KB < 2; ++KB) {
                d = __builtin_amdgcn_mfma_f32_16x16x32_bf16(Af[Ro][KB].v, Bd[KB][Co].v, d, 0, 0, 0);
                d = __builtin_amdgcn_mfma_f32_16x16x32_bf16(Af[Ro][KB].v, B2[KB][Co].v, d, 0, 0, 0);
            }
            acc[Ro][Co] = d;
        }
}

// ================= fused kernel: one block per sentence =================
// 4 waves; wave w computes T_w = (prod of words 16w..16w+15)^T with a
// triple-buffered DMA pipeline (prefetch depth 2; in-loop vmcnt(8) never
// drains to 0), publishes T_w to LDS, then all waves redundantly combine
// X = P0*P1*P2*P3 (3 stepT's); wave 0 stores.
// LDS: 4 waves x 3 x 3328 B = 39936 B -> exactly 4 blocks/CU: the whole
// 1024-block grid is resident in one pass (16 waves/CU).
__global__ __launch_bounds__(NW * 64, 4) void w2m_fusedT3(
    const int* __restrict__ sent,
    const float* __restrict__ table,
    float* __restrict__ out)
{
    __shared__ float SH[NW * 3 * BUFF] __attribute__((aligned(16)));
    const int lane = threadIdx.x & 63;
    const int wid  = threadIdx.x >> 6;   // 0..3
    const int b = blockIdx.x;
    const int c = lane & 15;
    const int quad = lane >> 4;
    const bool q3 = (quad == 3);
    const int qc = q3 ? 2 : quad;        // clamp so chain a1 reads stay <832

    float* B0 = &SH[wid * 3 * BUFF];
    float* B1 = B0 + BUFF;
    float* B2b = B0 + 2 * BUFF;

    const int myidx = sent[b * SEQ + CH * wid + (lane & (CH - 1))];
    int jl[CH];
#pragma unroll
    for (int j = 0; j < CH; ++j) jl[j] = __builtin_amdgcn_readlane(myidx, j);

    // ---- prologue: 3 rows in flight
    dma_row(table + (size_t)jl[0] * EMB, B0, lane);
    dma_row(table + (size_t)jl[1] * EMB, B1, lane);
    dma_row(table + (size_t)jl[2] * EMB, B2b, lane);
    __builtin_amdgcn_s_waitcnt(0x0078);  // vmcnt(8): row0 landed, rows1-2 in flight

    // init: acc = M0^T (b128 reads; row clamp -> junk only in pad cols,
    // masked at store; pad rows get A-side zeros every step).
    float4v acc[2][2];
#pragma unroll
    for (int R = 0; R < 2; ++R)
#pragma unroll
        for (int Cc = 0; Cc < 2; ++Cc) {
            int rcl = 16 * Cc + c; if (rcl > 27) rcl = 27;
            acc[R][Cc] = *(const float4v*)&B0[rcl * D + 16 * R + 4 * quad];
        }

    // per-lane, per-buffer A bases (all step offsets become immediates)
    const float* a00 = B0  + 4 * quad * D + c;
    const float* a10 = B0  + (16 + 4 * qc) * D + c;
    const float* a01 = B1  + 4 * quad * D + c;
    const float* a11 = B1  + (16 + 4 * qc) * D + c;
    const float* a02 = B2b + 4 * quad * D + c;
    const float* a12 = B2b + (16 + 4 * qc) * D + c;

    // ---- chain: fully unrolled (jl[] indices + buffers compile-time).
    // Per step: (a) lgkmcnt(0) BEFORE the DMA issue — guarantees the previous
    // step's ds_reads of the buffer this DMA overwrites are complete (closes
    // the one formal race of the triple-buffer scheme, ~free since those
    // reads were issued a full step earlier); (b) issue 4 loads; (c) wait
    // vmcnt(8): row j landed, rows j+1, j+2 stay in flight across the step.
#pragma unroll
    for (int j = 1; j < CH; ++j) {
        __builtin_amdgcn_s_waitcnt(0xC07F);  // lgkmcnt(0): prior reads done
        const int jn = (j + 2 < CH) ? j + 2 : CH - 1;  // tail re-issues row 15
        const int tb = (j + 2) % 3;                    // row r -> buffer r%3
        float* nB = (tb == 0) ? B0 : (tb == 1) ? B1 : B2b;
        dma_row(table + (size_t)jl[jn] * EMB, nB, lane);

        __builtin_amdgcn_sched_barrier(0);
        __builtin_amdgcn_s_waitcnt(0x0078);  // vmcnt(8) lgkmcnt(0)
        __builtin_amdgcn_sched_barrier(0);

        const int cb = j % 3;
        if (cb == 0)      stepT<D>(a00, a10, acc, q3);
        else if (cb == 1) stepT<D>(a01, a11, acc, q3);
        else              stepT<D>(a02, a12, acc, q3);
    }

    // ---- publish T_w row-major (stride 36) into own region (overwrites
    // B-bufs; 1148 <= 2496 floats). Drain all DMA (incl. tail dups) first.
    __builtin_amdgcn_s_waitcnt(0x0070);  // vmcnt(0) lgkmcnt(0)
    __builtin_amdgcn_sched_barrier(0);
    float* SCR = B0;
#pragma unroll
    for (int R = 0; R < 2; ++R)
#pragma unroll
        for (int Cc = 0; Cc < 2; ++Cc)
#pragma unroll
            for (int i = 0; i < 4; ++i)
                SCR[(16 * R + 4 * quad + i) * SCRW + 16 * Cc + c] = acc[R][Cc][i];
    __syncthreads();

    // ---- combine (redundant on all waves): X = P3, then X = Pj*X, j=2,1,0.
    const float* S3 = &SH[3 * 3 * BUFF];
#pragma unroll
    for (int R = 0; R < 2; ++R)
#pragma unroll
        for (int Cc = 0; Cc < 2; ++Cc)
            acc[R][Cc] = *(const float4v*)&S3[(16 * Cc + c) * SCRW + 16 * R + 4 * quad];

#pragma unroll
    for (int j = 2; j >= 0; --j) {
        const float* reg = &SH[j * 3 * BUFF];
        // scratch region is 2496 floats: unclamped a1 (max off 1147) in-bounds;
        // junk rows 28..31 zeroed by stepT's q3 path.
        stepT<SCRW>(reg + 4 * quad * SCRW + c,
                    reg + (16 + 4 * quad) * SCRW + c, acc, q3);
    }

    // ---- store rows/cols < 28
    if (wid == 0) {
        float* orow = out + (size_t)b * EMB;
#pragma unroll
        for (int R = 0; R < 2; ++R)
#pragma unroll
            for (int Cc = 0; Cc < 2; ++Cc)
#pragma unroll
                for (int i = 0; i < 4; ++i) {
                    const int row = 16 * R + 4 * quad + i;
                    const int col = 16 * Cc + c;
                    if (row < D && col < D) orow[row * D + col] = acc[R][Cc][i];
                }
    }
}

extern "C" void kernel_launch(void* const* d_in, const int* in_sizes, int n_in,
                              void* d_out, int out_size, void* d_ws, size_t ws_size,
                              hipStream_t stream) {
    const int* sent = (const int*)d_in[0];
    const float* table = (const float*)d_in[1];
    float* out = (float*)d_out;
    const int batch = in_sizes[0] / SEQ;                  // 1024
    (void)d_ws; (void)ws_size;                            // workspace unused

    hipLaunchKernelGGL(w2m_fusedT3, dim3(batch), dim3(NW * 64), 0, stream,
                       sent, table, out);
}